// Round 4
// baseline (283.669 us; speedup 1.0000x reference)
//
#include <hip/hip_runtime.h>

// Problem dims (fixed by setup_inputs)
#define HH 384
#define WW 512
#define NB 4
#define HWP (HH * WW)       // 196608
#define NPIX (NB * HWP)     // 786432
#define SH 96
#define SW 128
#define SHW (SH * SW)

// Row-banded gather parameters
#define MBOUND 40           // |fy| < 40 handled by banded gather; rest -> overflow list
#define BAND 4              // target rows per block
#define NBANDS (HH / BAND)  // 96
#define OV_CAP 65536        // overflow record capacity (expected ~10 used)

// Strict-IEEE f32 bilinear 4x upsample of (10*flow) — bit-identical to the
// passing round-3 version. Do not touch: floor decisions depend on it.
static __device__ __forceinline__ float upsample_flow_f32(const float* __restrict__ f, int y, int x) {
    float sx = __fadd_rn(__fmul_rn((float)x, 0.25f), -0.375f);  // exact
    float sy = __fadd_rn(__fmul_rn((float)y, 0.25f), -0.375f);  // exact
    float fx0 = floorf(sx), fy0 = floorf(sy);
    float wx = __fsub_rn(sx, fx0);   // exact: {0.625,0.875,0.125,0.375}
    float wy = __fsub_rn(sy, fy0);
    int ix = (int)fx0, iy = (int)fy0;
    int x0 = max(ix, 0), x1 = min(ix + 1, SW - 1);
    int y0 = max(iy, 0), y1 = min(iy + 1, SH - 1);
    float v00 = __fmul_rn(10.0f, f[y0 * SW + x0]);
    float v01 = __fmul_rn(10.0f, f[y0 * SW + x1]);
    float v10 = __fmul_rn(10.0f, f[y1 * SW + x0]);
    float v11 = __fmul_rn(10.0f, f[y1 * SW + x1]);
    float omx = __fsub_rn(1.0f, wx);
    float omy = __fsub_rn(1.0f, wy);
    float w00 = __fmul_rn(omx, omy);
    float w10 = __fmul_rn(wx, omy);
    float w01 = __fmul_rn(omx, wy);
    float w11 = __fmul_rn(wx, wy);
    float s = __fmul_rn(w00, v00);
    s = __fadd_rn(s, __fmul_rn(w10, v01));
    s = __fadd_rn(s, __fmul_rn(w01, v10));
    s = __fadd_rn(s, __fmul_rn(w11, v11));
    return s;
}

// Phase 1: materialize upsampled flow (plain coalesced stores, no atomics).
// Fu layout: [side][comp][b][h][w]. Rare |fy|>=MBOUND valid pixels go to an
// exact overflow list living in the (currently dead) output buffer.
__global__ __launch_bounds__(256) void upsample_k(const float* __restrict__ flow01,
                                                  const float* __restrict__ flow10,
                                                  float* __restrict__ Fu, float* __restrict__ ovf) {
    int idx = blockIdx.x * blockDim.x + threadIdx.x;
    if (idx >= NPIX) return;
    int side = blockIdx.y;
    const float* flow = side ? flow10 : flow01;
    int x = idx % WW;
    int y = (idx / WW) % HH;
    int b = idx / HWP;
    const float* fp = flow + b * 2 * SHW;
    float fx = upsample_flow_f32(fp, y, x);
    float fy = upsample_flow_f32(fp + SHW, y, x);
    float* F = Fu + side * 2 * NPIX;
    F[idx] = fx;
    F[NPIX + idx] = fy;
    float x2 = __fadd_rn((float)x, fx);
    float y2 = __fadd_rn((float)y, fy);
    bool valid = (x2 >= 0.0f && x2 <= (float)(WW - 1) && y2 >= 0.0f && y2 <= (float)(HH - 1));
    bool banded = (fy >= -(float)MBOUND && fy < (float)MBOUND);
    if (valid && !banded) {
        int xf = (int)floorf(x2);
        int yf = (int)floorf(y2);
        int key = side * NPIX + b * HWP + yf * WW + xf;
        int slot = atomicAdd((int*)ovf, 1);
        if (slot >= 0 && slot < OV_CAP) {
            ((int*)ovf)[64 + slot] = key;
            ovf[64 + OV_CAP + slot] = -fx;
            ovf[64 + 2 * OV_CAP + slot] = -fy;
        }
    }
}

// Phase 2: one block per (side, b, 4-row target band). LDS band histogram with
// LDS atomics; overflow replay; plain coalesced G stores. No global atomics,
// no G memset. XCD-chunked blockIdx mapping (slab = bid&7) for L2 locality.
__global__ __launch_bounds__(256) void row_gather_k(const float* __restrict__ Fu,
                                                    const float* __restrict__ ovf,
                                                    float* __restrict__ g0, float* __restrict__ g1) {
    __shared__ float acc[3][BAND][WW];   // 24 KB
    int bid = blockIdx.x;                // 768 blocks
    int slab = bid & 7;
    int side = slab >> 2;
    int b = slab & 3;
    int t0 = (bid >> 3) * BAND;

    const float* Fx = Fu + side * 2 * NPIX + b * HWP;
    const float* Fyp = Fx + NPIX;

    float* A = &acc[0][0][0];
    for (int k = threadIdx.x; k < 3 * BAND * WW; k += 256) A[k] = 0.0f;
    __syncthreads();

    int sLo = max(t0 - MBOUND, 0);
    int sHi = min(t0 + BAND - 1 + MBOUND, HH - 1);
    for (int s = sLo; s <= sHi; ++s) {
        int rowoff = s * WW + 2 * threadIdx.x;
        float2 fxv = *(const float2*)(Fx + rowoff);
        float2 fyv = *(const float2*)(Fyp + rowoff);
        float sf = (float)s;
        #pragma unroll
        for (int u = 0; u < 2; ++u) {
            int xx = 2 * threadIdx.x + u;
            float fx = u ? fxv.y : fxv.x;
            float fy = u ? fyv.y : fyv.x;
            float x2 = __fadd_rn((float)xx, fx);
            float y2 = __fadd_rn(sf, fy);
            if (x2 >= 0.0f && x2 <= (float)(WW - 1) && y2 >= 0.0f && y2 <= (float)(HH - 1)
                && fy >= -(float)MBOUND && fy < (float)MBOUND) {
                int yf = (int)floorf(y2);
                int r = yf - t0;
                if (r >= 0 && r < BAND) {
                    int xf = (int)floorf(x2);
                    atomicAdd(&acc[0][r][xf], -fx);
                    atomicAdd(&acc[1][r][xf], -fy);
                    atomicAdd(&acc[2][r][xf], 1.0f);
                }
            }
        }
    }

    // replay exact overflow records that land in this band
    int n = ((const int*)ovf)[0];
    n = (n < 0) ? 0 : ((n > OV_CAP) ? OV_CAP : n);
    int lo = t0 * WW, hi = (t0 + BAND) * WW;
    int keybase = side * NPIX + b * HWP;
    for (int i = threadIdx.x; i < n; i += 256) {
        int rel = ((const int*)ovf)[64 + i] - keybase;
        if (rel >= lo && rel < hi) {
            int r = rel / WW - t0;
            int xf = rel % WW;
            atomicAdd(&acc[0][r][xf], ovf[64 + OV_CAP + i]);
            atomicAdd(&acc[1][r][xf], ovf[64 + 2 * OV_CAP + i]);
            atomicAdd(&acc[2][r][xf], 1.0f);
        }
    }
    __syncthreads();

    float* G = (side ? g1 : g0) + b * HWP;
    for (int k = threadIdx.x; k < 3 * BAND * WW; k += 256) {
        int plane = k / (BAND * WW);
        int rem = k % (BAND * WW);
        G[plane * NPIX + t0 * WW + rem] = A[k];
    }
}

// 2x2 weighted box-sum of G == the reference's 4-neighbor scatter result.
static __device__ __forceinline__ void box_sum(const float* __restrict__ G, int b, int y, int x,
                                               float& ax, float& ay, float& c) {
    const float* Gx = G;
    const float* Gy = G + NPIX;
    const float* Gc = G + 2 * NPIX;
    float wxs1 = (x == WW - 1) ? 2.0f : 1.0f;
    float wys1 = (y == HH - 1) ? 2.0f : 1.0f;
    float sx = 0.0f, sy = 0.0f, sc = 0.0f;
    int base = b * HWP;
    #pragma unroll
    for (int j = 0; j < 2; j++) {
        int ey = y - 1 + j;
        if (ey < 0) continue;
        float wy = j ? wys1 : 1.0f;
        #pragma unroll
        for (int i = 0; i < 2; i++) {
            int ex = x - 1 + i;
            if (ex < 0) continue;
            float w = wy * ((i ? wxs1 : 1.0f));   // exact
            int o = base + ey * WW + ex;
            sx += w * Gx[o];
            sy += w * Gy[o];
            sc += w * Gc[o];
        }
    }
    ax = sx; ay = sy; c = sc;
}

// Fused fill2 + interp, ONE side per thread (z = side*NB + b, the round-2
// proven mapping: 1.57M threads for max memory-level parallelism). Ft is
// computed inline from G (bit-identical chain to the old fill2_k); results
// combine into out via unsafeAtomicAdd on a zeroed buffer (commutative
// two-term sum == plain-store combine bitwise).
__global__ __launch_bounds__(256) void interp2s_k(const float* __restrict__ img0,
                                                  const float* __restrict__ img2,
                                                  const float* __restrict__ filt0,
                                                  const float* __restrict__ filt1,
                                                  const float* __restrict__ g0,
                                                  const float* __restrict__ g1,
                                                  float* __restrict__ out) {
    int x = blockIdx.x * 64 + threadIdx.x;
    int y = blockIdx.y * 4 + threadIdx.y;
    int bz = blockIdx.z;
    int side = bz >> 2;          // NB == 4
    int b = bz & 3;
    const float* img  = side ? img2  : img0;
    const float* filt = side ? filt1 : filt0;
    const float* G    = side ? g1    : g0;

    // --- inline fill2: box-sum + avg + hole fill (bit-identical chain) ---
    float ax, ay, c;
    box_sum(G, b, y, x, ax, ay, c);
    float fx, fy;
    if (c > 0.0f) {
        fx = ax / c;
        fy = ay / c;
    } else {
        float nx = 0.0f, ny = 0.0f, den = 0.0f;
        float bx, by, bc;
        if (y > 0)      { box_sum(G, b, y - 1, x, bx, by, bc); if (bc > 0.0f) { nx += bx / bc; ny += by / bc; den += 1.0f; } }
        if (y < HH - 1) { box_sum(G, b, y + 1, x, bx, by, bc); if (bc > 0.0f) { nx += bx / bc; ny += by / bc; den += 1.0f; } }
        if (x > 0)      { box_sum(G, b, y, x - 1, bx, by, bc); if (bc > 0.0f) { nx += bx / bc; ny += by / bc; den += 1.0f; } }
        if (x < WW - 1) { box_sum(G, b, y, x + 1, bx, by, bc); if (bc > 0.0f) { nx += bx / bc; ny += by / bc; den += 1.0f; } }
        float inv = 1.0f / fmaxf(den, 1.0f);
        fx = nx * inv;
        fy = ny * inv;
    }

    // --- interp ---
    float x2 = fminf(fmaxf((float)x + fx, 0.0f), (float)(WW - 1));
    float y2 = fminf(fmaxf((float)y + fy, 0.0f), (float)(HH - 1));
    float xff = floorf(x2), yff = floorf(y2);
    int xf = (int)xff, yf = (int)yff;
    float a  = x2 - xff;
    float bb = y2 - yff;
    float w00 = (1.0f - a) * (1.0f - bb);
    float w10 = a * (1.0f - bb);
    float w01 = (1.0f - a) * bb;
    float w11 = a * bb;

    // load 4x4 filter taps for this pixel (coalesced per plane)
    float F[4][4];
    #pragma unroll
    for (int k = 0; k < 16; k++) {
        F[k >> 2][k & 3] = filt[((b * 16 + k) * HH + y) * WW + x];
    }
    // fold bilinear weights into a 5x5 effective coefficient map
    float Cf[5][5];
    #pragma unroll
    for (int r = 0; r < 5; r++) {
        #pragma unroll
        for (int sc = 0; sc < 5; sc++) {
            float v = 0.0f;
            if (r < 4 && sc < 4)   v += w00 * F[r][sc];
            if (r < 4 && sc >= 1)  v += w10 * F[r][sc - 1];
            if (r >= 1 && sc < 4)  v += w01 * F[r - 1][sc];
            if (r >= 1 && sc >= 1) v += w11 * F[r - 1][sc - 1];
            Cf[r][sc] = v;
        }
    }
    int rows[5];
    #pragma unroll
    for (int r = 0; r < 5; r++) rows[r] = min(max(yf - 1 + r, 0), HH - 1);

    bool interior = (xf >= 1) && (xf <= WW - 4);
    if (interior) {
        int x0 = xf - 1;   // cols are x0..x0+4, all in-bounds
        #pragma unroll
        for (int ch = 0; ch < 3; ch++) {
            const float* ip = img + (b * 3 + ch) * HWP;
            float accv = 0.0f;
            #pragma unroll
            for (int r = 0; r < 5; r++) {
                const float* rp = ip + rows[r] * WW + x0;
                float wrow[5];
                __builtin_memcpy(wrow, rp, 5 * sizeof(float));
                #pragma unroll
                for (int sc = 0; sc < 5; sc++) {
                    accv += Cf[r][sc] * wrow[sc];
                }
            }
            unsafeAtomicAdd(&out[((b * 3 + ch) * HH + y) * WW + x], 0.5f * accv);
        }
    } else {
        int cols[5];
        #pragma unroll
        for (int sc = 0; sc < 5; sc++) cols[sc] = min(max(xf - 1 + sc, 0), WW - 1);
        #pragma unroll
        for (int ch = 0; ch < 3; ch++) {
            const float* ip = img + (b * 3 + ch) * HWP;
            float accv = 0.0f;
            #pragma unroll
            for (int r = 0; r < 5; r++) {
                const float* rp = ip + rows[r] * WW;
                #pragma unroll
                for (int sc = 0; sc < 5; sc++) {
                    accv += Cf[r][sc] * rp[cols[sc]];
                }
            }
            unsafeAtomicAdd(&out[((b * 3 + ch) * HH + y) * WW + x], 0.5f * accv);
        }
    }
}

extern "C" void kernel_launch(void* const* d_in, const int* in_sizes, int n_in,
                              void* d_out, int out_size, void* d_ws, size_t ws_size,
                              hipStream_t stream) {
    const float* input0 = (const float*)d_in[0];
    const float* input2 = (const float*)d_in[1];
    const float* flow01 = (const float*)d_in[2];
    const float* flow10 = (const float*)d_in[3];
    const float* filt0  = (const float*)d_in[4];
    const float* filt1  = (const float*)d_in[5];
    float* out = (float*)d_out;

    float* ws = (float*)d_ws;
    float* g0   = ws;                    // 3*NPIX: Gx, Gy, Gc (side 0)
    float* g1   = ws + 3 * NPIX;         // 3*NPIX (side 1)
    float* Fu   = ws + 6 * NPIX;         // 4*NPIX: upsampled flow [side][comp][...]
    float* ovf  = out;                   // overflow counter+records live in dead out buf
                                         // (consumed by row_gather_k, then out is
                                         //  memset and accumulated by interp2s_k)

    const int BS = 256;
    const int NBLK = (NPIX + BS - 1) / BS;

    hipMemsetAsync(ovf, 0, 256, stream);

    upsample_k<<<dim3(NBLK, 2), BS, 0, stream>>>(flow01, flow10, Fu, ovf);
    row_gather_k<<<dim3(2 * NB * NBANDS), BS, 0, stream>>>(Fu, ovf, g0, g1);
    hipMemsetAsync(out, 0, (size_t)3 * NPIX * sizeof(float), stream);
    interp2s_k<<<dim3(WW / 64, HH / 4, NB * 2), dim3(64, 4), 0, stream>>>(
        input0, input2, filt0, filt1, g0, g1, out);
}

// Round 5
// 277.365 us; speedup vs baseline: 1.0227x; 1.0227x over previous
//
#include <hip/hip_runtime.h>

// Problem dims (fixed by setup_inputs)
#define HH 384
#define WW 512
#define NB 4
#define HWP (HH * WW)       // 196608
#define NPIX (NB * HWP)     // 786432
#define SH 96
#define SW 128
#define SHW (SH * SW)

// Row-banded gather parameters
#define MBOUND 40           // |fy| < 40 handled by banded gather; rest -> overflow list
#define BAND 4              // target rows per block
#define NBANDS (HH / BAND)  // 96
#define NROWS (BAND + 3)    // LDS rows t0-2 .. t0+4 (halo for in-LDS fill)
#define OV_CAP 65536        // overflow record capacity (expected ~10 used)

// Strict-IEEE f32 bilinear 4x upsample of (10*flow) — bit-identical to the
// passing version. Do not touch: floor decisions depend on it.
static __device__ __forceinline__ float upsample_flow_f32(const float* __restrict__ f, int y, int x) {
    float sx = __fadd_rn(__fmul_rn((float)x, 0.25f), -0.375f);  // exact
    float sy = __fadd_rn(__fmul_rn((float)y, 0.25f), -0.375f);  // exact
    float fx0 = floorf(sx), fy0 = floorf(sy);
    float wx = __fsub_rn(sx, fx0);   // exact: {0.625,0.875,0.125,0.375}
    float wy = __fsub_rn(sy, fy0);
    int ix = (int)fx0, iy = (int)fy0;
    int x0 = max(ix, 0), x1 = min(ix + 1, SW - 1);
    int y0 = max(iy, 0), y1 = min(iy + 1, SH - 1);
    float v00 = __fmul_rn(10.0f, f[y0 * SW + x0]);
    float v01 = __fmul_rn(10.0f, f[y0 * SW + x1]);
    float v10 = __fmul_rn(10.0f, f[y1 * SW + x0]);
    float v11 = __fmul_rn(10.0f, f[y1 * SW + x1]);
    float omx = __fsub_rn(1.0f, wx);
    float omy = __fsub_rn(1.0f, wy);
    float w00 = __fmul_rn(omx, omy);
    float w10 = __fmul_rn(wx, omy);
    float w01 = __fmul_rn(omx, wy);
    float w11 = __fmul_rn(wx, wy);
    float s = __fmul_rn(w00, v00);
    s = __fadd_rn(s, __fmul_rn(w10, v01));
    s = __fadd_rn(s, __fmul_rn(w01, v10));
    s = __fadd_rn(s, __fmul_rn(w11, v11));
    return s;
}

// Phase 1: materialize upsampled flow (plain coalesced stores, no atomics).
// Fu layout: [side][comp][b][h][w]. Rare |fy|>=MBOUND valid pixels go to an
// exact overflow list living in the (currently dead) output buffer.
__global__ __launch_bounds__(256) void upsample_k(const float* __restrict__ flow01,
                                                  const float* __restrict__ flow10,
                                                  float* __restrict__ Fu, float* __restrict__ ovf) {
    int idx = blockIdx.x * blockDim.x + threadIdx.x;
    if (idx >= NPIX) return;
    int side = blockIdx.y;
    const float* flow = side ? flow10 : flow01;
    int x = idx % WW;
    int y = (idx / WW) % HH;
    int b = idx / HWP;
    const float* fp = flow + b * 2 * SHW;
    float fx = upsample_flow_f32(fp, y, x);
    float fy = upsample_flow_f32(fp + SHW, y, x);
    float* F = Fu + side * 2 * NPIX;
    F[idx] = fx;
    F[NPIX + idx] = fy;
    float x2 = __fadd_rn((float)x, fx);
    float y2 = __fadd_rn((float)y, fy);
    bool valid = (x2 >= 0.0f && x2 <= (float)(WW - 1) && y2 >= 0.0f && y2 <= (float)(HH - 1));
    bool banded = (fy >= -(float)MBOUND && fy < (float)MBOUND);
    if (valid && !banded) {
        int xf = (int)floorf(x2);
        int yf = (int)floorf(y2);
        int key = side * NPIX + b * HWP + yf * WW + xf;
        int slot = atomicAdd((int*)ovf, 1);
        if (slot >= 0 && slot < OV_CAP) {
            ((int*)ovf)[64 + slot] = key;
            ovf[64 + OV_CAP + slot] = -fx;
            ovf[64 + 2 * OV_CAP + slot] = -fy;
        }
    }
}

// 2x2 weighted box-sum over the LDS band histogram == the reference's
// 4-neighbor scatter sum. Identical add order/weights to the proven global
// version; only the storage moved to LDS.
static __device__ __forceinline__ void box_sum_lds(const float (&acc)[3][NROWS][WW], int rbase,
                                                   int y, int x, float& ax, float& ay, float& c) {
    float wxs1 = (x == WW - 1) ? 2.0f : 1.0f;
    float wys1 = (y == HH - 1) ? 2.0f : 1.0f;
    float sx = 0.0f, sy = 0.0f, sc = 0.0f;
    #pragma unroll
    for (int j = 0; j < 2; j++) {
        int ey = y - 1 + j;
        if (ey < 0) continue;
        float wy = j ? wys1 : 1.0f;
        int rr = ey - rbase;   // in [0, NROWS-1] by construction
        #pragma unroll
        for (int i = 0; i < 2; i++) {
            int ex = x - 1 + i;
            if (ex < 0) continue;
            float w = wy * ((i ? wxs1 : 1.0f));   // exact
            sx += w * acc[0][rr][ex];
            sy += w * acc[1][rr][ex];
            sc += w * acc[2][rr][ex];
        }
    }
    ax = sx; ay = sy; c = sc;
}

// Phase 2 (fused): one block per (side, b, 4-row band). Build the deposit
// histogram for rows [t0-2, t0+4] (band + halo) in LDS via LDS atomics,
// replay the overflow list, then compute fill (box-sum + avg + hole fill)
// ENTIRELY from LDS and write Ft directly. G never touches global memory.
// XCD-chunked blockIdx mapping (slab = bid&7) keeps each slab L2-resident.
__global__ __launch_bounds__(256) void row_gather_fill_k(const float* __restrict__ Fu,
                                                         const float* __restrict__ ovf,
                                                         float* __restrict__ Ft0,
                                                         float* __restrict__ Ft2) {
    __shared__ float acc[3][NROWS][WW];   // 42 KB
    int bid = blockIdx.x;                 // 768 blocks
    int slab = bid & 7;
    int side = slab >> 2;
    int b = slab & 3;
    int t0 = (bid >> 3) * BAND;
    int rbase = t0 - 2;                   // global row of acc row 0

    const float* Fx = Fu + side * 2 * NPIX + b * HWP;
    const float* Fyp = Fx + NPIX;

    float* A = &acc[0][0][0];
    for (int k = threadIdx.x; k < 3 * NROWS * WW; k += 256) A[k] = 0.0f;
    __syncthreads();

    // sources for target rows [t0-2, t0+4] with floor(fy) in [-40,39]:
    // s in [t0-41, t0+44]
    int sLo = max(t0 - 2 - (MBOUND - 1), 0);
    int sHi = min(t0 + BAND + MBOUND, HH - 1);
    for (int s = sLo; s <= sHi; ++s) {
        int rowoff = s * WW + 2 * threadIdx.x;
        float2 fxv = *(const float2*)(Fx + rowoff);
        float2 fyv = *(const float2*)(Fyp + rowoff);
        float sf = (float)s;
        #pragma unroll
        for (int u = 0; u < 2; ++u) {
            int xx = 2 * threadIdx.x + u;
            float fx = u ? fxv.y : fxv.x;
            float fy = u ? fyv.y : fyv.x;
            float x2 = __fadd_rn((float)xx, fx);
            float y2 = __fadd_rn(sf, fy);
            if (x2 >= 0.0f && x2 <= (float)(WW - 1) && y2 >= 0.0f && y2 <= (float)(HH - 1)
                && fy >= -(float)MBOUND && fy < (float)MBOUND) {
                int yf = (int)floorf(y2);
                int r = yf - rbase;
                if (r >= 0 && r < NROWS) {
                    int xf = (int)floorf(x2);
                    atomicAdd(&acc[0][r][xf], -fx);
                    atomicAdd(&acc[1][r][xf], -fy);
                    atomicAdd(&acc[2][r][xf], 1.0f);
                }
            }
        }
    }

    // replay exact overflow records landing in [max(rbase,0), min(t0+4,HH-1)]
    int n = ((const int*)ovf)[0];
    n = (n < 0) ? 0 : ((n > OV_CAP) ? OV_CAP : n);
    int lo = max(rbase, 0) * WW;
    int hi = (min(t0 + BAND, HH - 1) + 1) * WW;
    int keybase = side * NPIX + b * HWP;
    for (int i = threadIdx.x; i < n; i += 256) {
        int rel = ((const int*)ovf)[64 + i] - keybase;
        if (rel >= lo && rel < hi) {
            int r = rel / WW - rbase;
            int xf = rel % WW;
            atomicAdd(&acc[0][r][xf], ovf[64 + OV_CAP + i]);
            atomicAdd(&acc[1][r][xf], ovf[64 + 2 * OV_CAP + i]);
            atomicAdd(&acc[2][r][xf], 1.0f);
        }
    }
    __syncthreads();

    // in-LDS fill for band rows t0..t0+3 (bit-identical chain to fill2_k)
    float* Ft = side ? Ft2 : Ft0;
    for (int k = threadIdx.x; k < BAND * WW; k += 256) {
        int y = t0 + k / WW;
        int x = k % WW;
        float ax, ay, c;
        box_sum_lds(acc, rbase, y, x, ax, ay, c);
        float fx, fy;
        if (c > 0.0f) {
            fx = ax / c;
            fy = ay / c;
        } else {
            float nx = 0.0f, ny = 0.0f, den = 0.0f;
            float bx, by, bc;
            if (y > 0)      { box_sum_lds(acc, rbase, y - 1, x, bx, by, bc); if (bc > 0.0f) { nx += bx / bc; ny += by / bc; den += 1.0f; } }
            if (y < HH - 1) { box_sum_lds(acc, rbase, y + 1, x, bx, by, bc); if (bc > 0.0f) { nx += bx / bc; ny += by / bc; den += 1.0f; } }
            if (x > 0)      { box_sum_lds(acc, rbase, y, x - 1, bx, by, bc); if (bc > 0.0f) { nx += bx / bc; ny += by / bc; den += 1.0f; } }
            if (x < WW - 1) { box_sum_lds(acc, rbase, y, x + 1, bx, by, bc); if (bc > 0.0f) { nx += bx / bc; ny += by / bc; den += 1.0f; } }
            float inv = 1.0f / fmaxf(den, 1.0f);
            fx = nx * inv;
            fy = ny * inv;
        }
        int o = b * HWP + y * WW + x;
        Ft[o] = fx;
        Ft[NPIX + o] = fy;
    }
}

// Filter interpolation, one side per block (blockIdx.z = side*NB + b),
// 1 pixel/thread, 64x4 tile — the round-2-proven 79.7 µs configuration.
__global__ void interp_k(const float* __restrict__ img0, const float* __restrict__ img2,
                         const float* __restrict__ filt0, const float* __restrict__ filt1,
                         const float* __restrict__ Ft0, const float* __restrict__ Ft2,
                         float* __restrict__ out) {
    int x = blockIdx.x * 64 + threadIdx.x;
    int y = blockIdx.y * 4 + threadIdx.y;
    int bz = blockIdx.z;
    int side = bz >> 2;          // NB == 4
    int b = bz & 3;
    const float* img  = side ? img2  : img0;
    const float* filt = side ? filt1 : filt0;
    const float* Ft   = side ? Ft2   : Ft0;

    int idx = b * HWP + y * WW + x;
    float fx = Ft[idx];
    float fy = Ft[NPIX + idx];
    float x2 = fminf(fmaxf((float)x + fx, 0.0f), (float)(WW - 1));
    float y2 = fminf(fmaxf((float)y + fy, 0.0f), (float)(HH - 1));
    float xff = floorf(x2), yff = floorf(y2);
    int xf = (int)xff, yf = (int)yff;
    float a  = x2 - xff;
    float bb = y2 - yff;
    float w00 = (1.0f - a) * (1.0f - bb);
    float w10 = a * (1.0f - bb);
    float w01 = (1.0f - a) * bb;
    float w11 = a * bb;

    // load 4x4 filter taps for this pixel (coalesced per plane)
    float F[4][4];
    #pragma unroll
    for (int k = 0; k < 16; k++) {
        F[k >> 2][k & 3] = filt[((b * 16 + k) * HH + y) * WW + x];
    }
    // fold bilinear weights into a 5x5 effective coefficient map
    float Cf[5][5];
    #pragma unroll
    for (int r = 0; r < 5; r++) {
        #pragma unroll
        for (int sc = 0; sc < 5; sc++) {
            float v = 0.0f;
            if (r < 4 && sc < 4)   v += w00 * F[r][sc];
            if (r < 4 && sc >= 1)  v += w10 * F[r][sc - 1];
            if (r >= 1 && sc < 4)  v += w01 * F[r - 1][sc];
            if (r >= 1 && sc >= 1) v += w11 * F[r - 1][sc - 1];
            Cf[r][sc] = v;
        }
    }
    int rows[5];
    #pragma unroll
    for (int r = 0; r < 5; r++) rows[r] = min(max(yf - 1 + r, 0), HH - 1);

    bool interior = (xf >= 1) && (xf <= WW - 4);
    if (interior) {
        int x0 = xf - 1;   // cols are x0..x0+4, all in-bounds
        #pragma unroll
        for (int c = 0; c < 3; c++) {
            const float* ip = img + (b * 3 + c) * HWP;
            float accv = 0.0f;
            #pragma unroll
            for (int r = 0; r < 5; r++) {
                const float* rp = ip + rows[r] * WW + x0;
                float wrow[5];
                __builtin_memcpy(wrow, rp, 5 * sizeof(float));
                #pragma unroll
                for (int sc = 0; sc < 5; sc++) {
                    accv += Cf[r][sc] * wrow[sc];
                }
            }
            unsafeAtomicAdd(&out[((b * 3 + c) * HH + y) * WW + x], 0.5f * accv);
        }
    } else {
        int cols[5];
        #pragma unroll
        for (int sc = 0; sc < 5; sc++) cols[sc] = min(max(xf - 1 + sc, 0), WW - 1);
        #pragma unroll
        for (int c = 0; c < 3; c++) {
            const float* ip = img + (b * 3 + c) * HWP;
            float accv = 0.0f;
            #pragma unroll
            for (int r = 0; r < 5; r++) {
                const float* rp = ip + rows[r] * WW;
                #pragma unroll
                for (int sc = 0; sc < 5; sc++) {
                    accv += Cf[r][sc] * rp[cols[sc]];
                }
            }
            unsafeAtomicAdd(&out[((b * 3 + c) * HH + y) * WW + x], 0.5f * accv);
        }
    }
}

extern "C" void kernel_launch(void* const* d_in, const int* in_sizes, int n_in,
                              void* d_out, int out_size, void* d_ws, size_t ws_size,
                              hipStream_t stream) {
    const float* input0 = (const float*)d_in[0];
    const float* input2 = (const float*)d_in[1];
    const float* flow01 = (const float*)d_in[2];
    const float* flow10 = (const float*)d_in[3];
    const float* filt0  = (const float*)d_in[4];
    const float* filt1  = (const float*)d_in[5];
    float* out = (float*)d_out;

    float* ws = (float*)d_ws;
    float* Fu   = ws;                    // 4*NPIX: upsampled flow [side][comp][...]
    float* Ft0  = ws + 4 * NPIX;         // 2*NPIX: Ftx, Fty (side 0)
    float* Ft2  = ws + 6 * NPIX;         // 2*NPIX (side 1)
    float* ovf  = out;                   // overflow counter+records live in dead out buf
                                         // (consumed by row_gather_fill_k, then out is
                                         //  memset and accumulated by interp_k)

    const int BS = 256;
    const int NBLK = (NPIX + BS - 1) / BS;

    hipMemsetAsync(ovf, 0, 256, stream);

    upsample_k<<<dim3(NBLK, 2), BS, 0, stream>>>(flow01, flow10, Fu, ovf);
    row_gather_fill_k<<<dim3(2 * NB * NBANDS), BS, 0, stream>>>(Fu, ovf, Ft0, Ft2);
    hipMemsetAsync(out, 0, (size_t)3 * NPIX * sizeof(float), stream);
    interp_k<<<dim3(WW / 64, HH / 4, NB * 2), dim3(64, 4), 0, stream>>>(
        input0, input2, filt0, filt1, Ft0, Ft2, out);
}

// Round 8
// 258.928 us; speedup vs baseline: 1.0956x; 1.0712x over previous
//
#include <hip/hip_runtime.h>

// Problem dims (fixed by setup_inputs)
#define HH 384
#define WW 512
#define NB 4
#define HWP (HH * WW)       // 196608
#define NPIX (NB * HWP)     // 786432
#define SH 96
#define SW 128
#define SHW (SH * SW)

// Row-banded gather parameters
#define MBOUND 24           // |fy| < 24 handled by banded gather; rest -> exact overflow list
#define BAND 6              // target rows per block
#define NBANDS (HH / BAND)  // 64
#define NROWS (BAND + 3)    // LDS rows t0-2 .. t0+6 (halo for in-LDS fill)
#define OV_CAP 131072       // overflow record capacity (expected ~3-6K used; >20x margin)

// Strict-IEEE f32 bilinear 4x upsample of (10*flow) — bit-identical to the
// passing version. Do not touch: floor decisions depend on it.
static __device__ __forceinline__ float upsample_flow_f32(const float* __restrict__ f, int y, int x) {
    float sx = __fadd_rn(__fmul_rn((float)x, 0.25f), -0.375f);  // exact
    float sy = __fadd_rn(__fmul_rn((float)y, 0.25f), -0.375f);  // exact
    float fx0 = floorf(sx), fy0 = floorf(sy);
    float wx = __fsub_rn(sx, fx0);   // exact: {0.625,0.875,0.125,0.375}
    float wy = __fsub_rn(sy, fy0);
    int ix = (int)fx0, iy = (int)fy0;
    int x0 = max(ix, 0), x1 = min(ix + 1, SW - 1);
    int y0 = max(iy, 0), y1 = min(iy + 1, SH - 1);
    float v00 = __fmul_rn(10.0f, f[y0 * SW + x0]);
    float v01 = __fmul_rn(10.0f, f[y0 * SW + x1]);
    float v10 = __fmul_rn(10.0f, f[y1 * SW + x0]);
    float v11 = __fmul_rn(10.0f, f[y1 * SW + x1]);
    float omx = __fsub_rn(1.0f, wx);
    float omy = __fsub_rn(1.0f, wy);
    float w00 = __fmul_rn(omx, omy);
    float w10 = __fmul_rn(wx, omy);
    float w01 = __fmul_rn(omx, wy);
    float w11 = __fmul_rn(wx, wy);
    float s = __fmul_rn(w00, v00);
    s = __fadd_rn(s, __fmul_rn(w10, v01));
    s = __fadd_rn(s, __fmul_rn(w01, v10));
    s = __fadd_rn(s, __fmul_rn(w11, v11));
    return s;
}

// Phase 1: materialize upsampled flow (plain coalesced stores, no atomics).
// Fu layout: [side][comp][b][h][w]. Valid pixels with |fy|>=MBOUND go to an
// exact overflow list living in the (currently dead) output buffer.
__global__ __launch_bounds__(256) void upsample_k(const float* __restrict__ flow01,
                                                  const float* __restrict__ flow10,
                                                  float* __restrict__ Fu, float* __restrict__ ovf) {
    int idx = blockIdx.x * blockDim.x + threadIdx.x;
    if (idx >= NPIX) return;
    int side = blockIdx.y;
    const float* flow = side ? flow10 : flow01;
    int x = idx % WW;
    int y = (idx / WW) % HH;
    int b = idx / HWP;
    const float* fp = flow + b * 2 * SHW;
    float fx = upsample_flow_f32(fp, y, x);
    float fy = upsample_flow_f32(fp + SHW, y, x);
    float* F = Fu + side * 2 * NPIX;
    F[idx] = fx;
    F[NPIX + idx] = fy;
    float x2 = __fadd_rn((float)x, fx);
    float y2 = __fadd_rn((float)y, fy);
    bool valid = (x2 >= 0.0f && x2 <= (float)(WW - 1) && y2 >= 0.0f && y2 <= (float)(HH - 1));
    bool banded = (fy >= -(float)MBOUND && fy < (float)MBOUND);
    if (valid && !banded) {
        int xf = (int)floorf(x2);
        int yf = (int)floorf(y2);
        int key = side * NPIX + b * HWP + yf * WW + xf;
        int slot = atomicAdd((int*)ovf, 1);
        if (slot >= 0 && slot < OV_CAP) {
            ((int*)ovf)[64 + slot] = key;
            ovf[64 + OV_CAP + slot] = -fx;
            ovf[64 + 2 * OV_CAP + slot] = -fy;
        }
    }
}

// 2x2 weighted box-sum over the LDS band histogram == the reference's
// 4-neighbor scatter sum. Identical add order/weights to the proven global
// version; only the storage moved to LDS.
static __device__ __forceinline__ void box_sum_lds(const float (&acc)[3][NROWS][WW], int rbase,
                                                   int y, int x, float& ax, float& ay, float& c) {
    float wxs1 = (x == WW - 1) ? 2.0f : 1.0f;
    float wys1 = (y == HH - 1) ? 2.0f : 1.0f;
    float sx = 0.0f, sy = 0.0f, sc = 0.0f;
    #pragma unroll
    for (int j = 0; j < 2; j++) {
        int ey = y - 1 + j;
        if (ey < 0) continue;
        float wy = j ? wys1 : 1.0f;
        int rr = ey - rbase;   // in [0, NROWS-1] by construction
        #pragma unroll
        for (int i = 0; i < 2; i++) {
            int ex = x - 1 + i;
            if (ex < 0) continue;
            float w = wy * ((i ? wxs1 : 1.0f));   // exact
            sx += w * acc[0][rr][ex];
            sy += w * acc[1][rr][ex];
            sc += w * acc[2][rr][ex];
        }
    }
    ax = sx; ay = sy; c = sc;
}

// Phase 2 (fused): one block per (side, b, 6-row band), 512 threads. Build
// the deposit histogram for rows [t0-2, t0+6] (band + halo) in LDS via LDS
// atomics (flat grid-stride scan over (row, col-pair) pairs), replay the
// exact overflow list, then compute fill (box-sum + avg + hole fill) from
// LDS and write Ft directly. 512 blocks = 2/CU all-resident (LDS 55.3 KB).
// XCD-chunked blockIdx mapping (slab = bid&7) keeps each slab L2-resident.
__global__ __launch_bounds__(512) void row_gather_fill_k(const float* __restrict__ Fu,
                                                         const float* __restrict__ ovf,
                                                         float* __restrict__ Ft0,
                                                         float* __restrict__ Ft2) {
    __shared__ float acc[3][NROWS][WW];   // 55.3 KB
    int bid = blockIdx.x;                 // 512 blocks
    int slab = bid & 7;
    int side = slab >> 2;
    int b = slab & 3;
    int t0 = (bid >> 3) * BAND;
    int rbase = t0 - 2;                   // global row of acc row 0

    const float* Fx = Fu + side * 2 * NPIX + b * HWP;
    const float* Fyp = Fx + NPIX;

    float* A = &acc[0][0][0];
    for (int k = threadIdx.x; k < 3 * NROWS * WW; k += 512) A[k] = 0.0f;
    __syncthreads();

    // sources for target rows [t0-2, t0+BAND] with floor(fy) in [-M, M-1]:
    // s in [t0-2-(M-1), t0+BAND+M]  (56 rows interior)
    int sLo = max(t0 - 2 - (MBOUND - 1), 0);
    int sHi = min(t0 + BAND + MBOUND, HH - 1);
    int npairs = (sHi - sLo + 1) * 256;   // (row, col-pair) work items
    for (int k = threadIdx.x; k < npairs; k += 512) {
        int s = sLo + (k >> 8);
        int tx = k & 255;
        int rowoff = s * WW + 2 * tx;
        float2 fxv = *(const float2*)(Fx + rowoff);
        float2 fyv = *(const float2*)(Fyp + rowoff);
        float sf = (float)s;
        #pragma unroll
        for (int u = 0; u < 2; ++u) {
            int xx = 2 * tx + u;
            float fx = u ? fxv.y : fxv.x;
            float fy = u ? fyv.y : fyv.x;
            float x2 = __fadd_rn((float)xx, fx);
            float y2 = __fadd_rn(sf, fy);
            if (x2 >= 0.0f && x2 <= (float)(WW - 1) && y2 >= 0.0f && y2 <= (float)(HH - 1)
                && fy >= -(float)MBOUND && fy < (float)MBOUND) {
                int yf = (int)floorf(y2);
                int r = yf - rbase;
                if (r >= 0 && r < NROWS) {
                    int xf = (int)floorf(x2);
                    atomicAdd(&acc[0][r][xf], -fx);
                    atomicAdd(&acc[1][r][xf], -fy);
                    atomicAdd(&acc[2][r][xf], 1.0f);
                }
            }
        }
    }

    // replay exact overflow records landing in [max(rbase,0), min(t0+BAND,HH-1)]
    int n = ((const int*)ovf)[0];
    n = (n < 0) ? 0 : ((n > OV_CAP) ? OV_CAP : n);
    int lo = max(rbase, 0) * WW;
    int hi = (min(t0 + BAND, HH - 1) + 1) * WW;
    int keybase = side * NPIX + b * HWP;
    for (int i = threadIdx.x; i < n; i += 512) {
        int rel = ((const int*)ovf)[64 + i] - keybase;
        if (rel >= lo && rel < hi) {
            int r = rel / WW - rbase;
            int xf = rel % WW;
            atomicAdd(&acc[0][r][xf], ovf[64 + OV_CAP + i]);
            atomicAdd(&acc[1][r][xf], ovf[64 + 2 * OV_CAP + i]);
            atomicAdd(&acc[2][r][xf], 1.0f);
        }
    }
    __syncthreads();

    // in-LDS fill for band rows t0..t0+BAND-1 (bit-identical chain to fill2_k)
    float* Ft = side ? Ft2 : Ft0;
    for (int k = threadIdx.x; k < BAND * WW; k += 512) {
        int y = t0 + k / WW;
        int x = k % WW;
        float ax, ay, c;
        box_sum_lds(acc, rbase, y, x, ax, ay, c);
        float fx, fy;
        if (c > 0.0f) {
            fx = ax / c;
            fy = ay / c;
        } else {
            float nx = 0.0f, ny = 0.0f, den = 0.0f;
            float bx, by, bc;
            if (y > 0)      { box_sum_lds(acc, rbase, y - 1, x, bx, by, bc); if (bc > 0.0f) { nx += bx / bc; ny += by / bc; den += 1.0f; } }
            if (y < HH - 1) { box_sum_lds(acc, rbase, y + 1, x, bx, by, bc); if (bc > 0.0f) { nx += bx / bc; ny += by / bc; den += 1.0f; } }
            if (x > 0)      { box_sum_lds(acc, rbase, y, x - 1, bx, by, bc); if (bc > 0.0f) { nx += bx / bc; ny += by / bc; den += 1.0f; } }
            if (x < WW - 1) { box_sum_lds(acc, rbase, y, x + 1, bx, by, bc); if (bc > 0.0f) { nx += bx / bc; ny += by / bc; den += 1.0f; } }
            float inv = 1.0f / fmaxf(den, 1.0f);
            fx = nx * inv;
            fy = ny * inv;
        }
        int o = b * HWP + y * WW + x;
        Ft[o] = fx;
        Ft[NPIX + o] = fy;
    }
}

// Filter interpolation, one side per block (blockIdx.z = side*NB + b),
// 1 pixel/thread, 64x4 tile — the round-2-proven 79.7 µs configuration.
__global__ __launch_bounds__(256) void interp_k(const float* __restrict__ img0,
                                                const float* __restrict__ img2,
                                                const float* __restrict__ filt0,
                                                const float* __restrict__ filt1,
                                                const float* __restrict__ Ft0,
                                                const float* __restrict__ Ft2,
                                                float* __restrict__ out) {
    int x = blockIdx.x * 64 + threadIdx.x;
    int y = blockIdx.y * 4 + threadIdx.y;
    int bz = blockIdx.z;
    int side = bz >> 2;          // NB == 4
    int b = bz & 3;
    const float* img  = side ? img2  : img0;
    const float* filt = side ? filt1 : filt0;
    const float* Ft   = side ? Ft2   : Ft0;

    int idx = b * HWP + y * WW + x;
    float fx = Ft[idx];
    float fy = Ft[NPIX + idx];
    float x2 = fminf(fmaxf((float)x + fx, 0.0f), (float)(WW - 1));
    float y2 = fminf(fmaxf((float)y + fy, 0.0f), (float)(HH - 1));
    float xff = floorf(x2), yff = floorf(y2);
    int xf = (int)xff, yf = (int)yff;
    float a  = x2 - xff;
    float bb = y2 - yff;
    float w00 = (1.0f - a) * (1.0f - bb);
    float w10 = a * (1.0f - bb);
    float w01 = (1.0f - a) * bb;
    float w11 = a * bb;

    // load 4x4 filter taps for this pixel (coalesced per plane)
    float F[4][4];
    #pragma unroll
    for (int k = 0; k < 16; k++) {
        F[k >> 2][k & 3] = filt[((b * 16 + k) * HH + y) * WW + x];
    }
    // fold bilinear weights into a 5x5 effective coefficient map
    float Cf[5][5];
    #pragma unroll
    for (int r = 0; r < 5; r++) {
        #pragma unroll
        for (int sc = 0; sc < 5; sc++) {
            float v = 0.0f;
            if (r < 4 && sc < 4)   v += w00 * F[r][sc];
            if (r < 4 && sc >= 1)  v += w10 * F[r][sc - 1];
            if (r >= 1 && sc < 4)  v += w01 * F[r - 1][sc];
            if (r >= 1 && sc >= 1) v += w11 * F[r - 1][sc - 1];
            Cf[r][sc] = v;
        }
    }
    int rows[5];
    #pragma unroll
    for (int r = 0; r < 5; r++) rows[r] = min(max(yf - 1 + r, 0), HH - 1);

    bool interior = (xf >= 1) && (xf <= WW - 4);
    if (interior) {
        int x0 = xf - 1;   // cols are x0..x0+4, all in-bounds
        #pragma unroll
        for (int c = 0; c < 3; c++) {
            const float* ip = img + (b * 3 + c) * HWP;
            float accv = 0.0f;
            #pragma unroll
            for (int r = 0; r < 5; r++) {
                const float* rp = ip + rows[r] * WW + x0;
                float wrow[5];
                __builtin_memcpy(wrow, rp, 5 * sizeof(float));
                #pragma unroll
                for (int sc = 0; sc < 5; sc++) {
                    accv += Cf[r][sc] * wrow[sc];
                }
            }
            unsafeAtomicAdd(&out[((b * 3 + c) * HH + y) * WW + x], 0.5f * accv);
        }
    } else {
        int cols[5];
        #pragma unroll
        for (int sc = 0; sc < 5; sc++) cols[sc] = min(max(xf - 1 + sc, 0), WW - 1);
        #pragma unroll
        for (int c = 0; c < 3; c++) {
            const float* ip = img + (b * 3 + c) * HWP;
            float accv = 0.0f;
            #pragma unroll
            for (int r = 0; r < 5; r++) {
                const float* rp = ip + rows[r] * WW;
                #pragma unroll
                for (int sc = 0; sc < 5; sc++) {
                    accv += Cf[r][sc] * rp[cols[sc]];
                }
            }
            unsafeAtomicAdd(&out[((b * 3 + c) * HH + y) * WW + x], 0.5f * accv);
        }
    }
}

extern "C" void kernel_launch(void* const* d_in, const int* in_sizes, int n_in,
                              void* d_out, int out_size, void* d_ws, size_t ws_size,
                              hipStream_t stream) {
    const float* input0 = (const float*)d_in[0];
    const float* input2 = (const float*)d_in[1];
    const float* flow01 = (const float*)d_in[2];
    const float* flow10 = (const float*)d_in[3];
    const float* filt0  = (const float*)d_in[4];
    const float* filt1  = (const float*)d_in[5];
    float* out = (float*)d_out;

    float* ws = (float*)d_ws;
    float* Fu   = ws;                    // 4*NPIX: upsampled flow [side][comp][...]
    float* Ft0  = ws + 4 * NPIX;         // 2*NPIX: Ftx, Fty (side 0)
    float* Ft2  = ws + 6 * NPIX;         // 2*NPIX (side 1)
    float* ovf  = out;                   // overflow counter+records live in dead out buf
                                         // (64 + 3*OV_CAP floats = 1.57 MB < 9.4 MB;
                                         //  consumed by row_gather_fill_k, then out is
                                         //  memset and accumulated by interp_k)

    const int BS = 256;
    const int NBLK = (NPIX + BS - 1) / BS;

    hipMemsetAsync(ovf, 0, 256, stream);

    upsample_k<<<dim3(NBLK, 2), BS, 0, stream>>>(flow01, flow10, Fu, ovf);
    row_gather_fill_k<<<dim3(2 * NB * NBANDS), 512, 0, stream>>>(Fu, ovf, Ft0, Ft2);
    hipMemsetAsync(out, 0, (size_t)3 * NPIX * sizeof(float), stream);
    interp_k<<<dim3(WW / 64, HH / 4, NB * 2), dim3(64, 4), 0, stream>>>(
        input0, input2, filt0, filt1, Ft0, Ft2, out);
}

// Round 9
// 250.536 us; speedup vs baseline: 1.1322x; 1.0335x over previous
//
#include <hip/hip_runtime.h>

// Problem dims (fixed by setup_inputs)
#define HH 384
#define WW 512
#define NB 4
#define HWP (HH * WW)       // 196608
#define NPIX (NB * HWP)     // 786432
#define SH 96
#define SW 128
#define SHW (SH * SW)

// Row-banded gather parameters
#define MBOUND 24           // |fy| < 24 handled by banded gather; rest -> exact overflow list
#define BAND 6              // target rows per block
#define NBANDS (HH / BAND)  // 64
#define NROWS (BAND + 3)    // LDS rows t0-2 .. t0+6 (halo for in-LDS fill)
#define OV_CAP 131072       // overflow record capacity (expected ~3-6K used; >20x margin)

// Strict-IEEE f32 bilinear 4x upsample of (10*flow) — bit-identical to the
// passing version. Do not touch: floor decisions depend on it.
static __device__ __forceinline__ float upsample_flow_f32(const float* __restrict__ f, int y, int x) {
    float sx = __fadd_rn(__fmul_rn((float)x, 0.25f), -0.375f);  // exact
    float sy = __fadd_rn(__fmul_rn((float)y, 0.25f), -0.375f);  // exact
    float fx0 = floorf(sx), fy0 = floorf(sy);
    float wx = __fsub_rn(sx, fx0);   // exact: {0.625,0.875,0.125,0.375}
    float wy = __fsub_rn(sy, fy0);
    int ix = (int)fx0, iy = (int)fy0;
    int x0 = max(ix, 0), x1 = min(ix + 1, SW - 1);
    int y0 = max(iy, 0), y1 = min(iy + 1, SH - 1);
    float v00 = __fmul_rn(10.0f, f[y0 * SW + x0]);
    float v01 = __fmul_rn(10.0f, f[y0 * SW + x1]);
    float v10 = __fmul_rn(10.0f, f[y1 * SW + x0]);
    float v11 = __fmul_rn(10.0f, f[y1 * SW + x1]);
    float omx = __fsub_rn(1.0f, wx);
    float omy = __fsub_rn(1.0f, wy);
    float w00 = __fmul_rn(omx, omy);
    float w10 = __fmul_rn(wx, omy);
    float w01 = __fmul_rn(omx, wy);
    float w11 = __fmul_rn(wx, wy);
    float s = __fmul_rn(w00, v00);
    s = __fadd_rn(s, __fmul_rn(w10, v01));
    s = __fadd_rn(s, __fmul_rn(w01, v10));
    s = __fadd_rn(s, __fmul_rn(w11, v11));
    return s;
}

// Phase 1: materialize upsampled flow (plain coalesced stores, no atomics).
// Fu layout: [side][comp][b][h][w]. Valid pixels with |fy|>=MBOUND go to an
// exact overflow list in the workspace (counter @ovf[0], keys @+64 ints,
// vx @+64+OV_CAP, vy @+64+2*OV_CAP).
__global__ __launch_bounds__(256) void upsample_k(const float* __restrict__ flow01,
                                                  const float* __restrict__ flow10,
                                                  float* __restrict__ Fu, float* __restrict__ ovf) {
    int idx = blockIdx.x * blockDim.x + threadIdx.x;
    if (idx >= NPIX) return;
    int side = blockIdx.y;
    const float* flow = side ? flow10 : flow01;
    int x = idx % WW;
    int y = (idx / WW) % HH;
    int b = idx / HWP;
    const float* fp = flow + b * 2 * SHW;
    float fx = upsample_flow_f32(fp, y, x);
    float fy = upsample_flow_f32(fp + SHW, y, x);
    float* F = Fu + side * 2 * NPIX;
    F[idx] = fx;
    F[NPIX + idx] = fy;
    float x2 = __fadd_rn((float)x, fx);
    float y2 = __fadd_rn((float)y, fy);
    bool valid = (x2 >= 0.0f && x2 <= (float)(WW - 1) && y2 >= 0.0f && y2 <= (float)(HH - 1));
    bool banded = (fy >= -(float)MBOUND && fy < (float)MBOUND);
    if (valid && !banded) {
        int xf = (int)floorf(x2);
        int yf = (int)floorf(y2);
        int key = side * NPIX + b * HWP + yf * WW + xf;
        int slot = atomicAdd((int*)ovf, 1);
        if (slot >= 0 && slot < OV_CAP) {
            ((int*)ovf)[64 + slot] = key;
            ovf[64 + OV_CAP + slot] = -fx;
            ovf[64 + 2 * OV_CAP + slot] = -fy;
        }
    }
}

// 2x2 weighted box-sum over the LDS band histogram == the reference's
// 4-neighbor scatter sum. Identical add order/weights to the proven global
// version; only the storage moved to LDS.
static __device__ __forceinline__ void box_sum_lds(const float (&acc)[3][NROWS][WW], int rbase,
                                                   int y, int x, float& ax, float& ay, float& c) {
    float wxs1 = (x == WW - 1) ? 2.0f : 1.0f;
    float wys1 = (y == HH - 1) ? 2.0f : 1.0f;
    float sx = 0.0f, sy = 0.0f, sc = 0.0f;
    #pragma unroll
    for (int j = 0; j < 2; j++) {
        int ey = y - 1 + j;
        if (ey < 0) continue;
        float wy = j ? wys1 : 1.0f;
        int rr = ey - rbase;   // in [0, NROWS-1] by construction
        #pragma unroll
        for (int i = 0; i < 2; i++) {
            int ex = x - 1 + i;
            if (ex < 0) continue;
            float w = wy * ((i ? wxs1 : 1.0f));   // exact
            sx += w * acc[0][rr][ex];
            sy += w * acc[1][rr][ex];
            sc += w * acc[2][rr][ex];
        }
    }
    ax = sx; ay = sy; c = sc;
}

// Phase 2 (fully fused): one block per (side, b, 6-row band), 512 threads.
// (a) Build the deposit histogram for rows [t0-2, t0+6] in LDS (LDS atomics),
// (b) replay the exact overflow list, (c) per pixel: in-LDS fill -> Ft, then
// IMMEDIATELY the 4x4-filter bilinear interp of that pixel, atomically
// combining 0.5*acc into out (memset-zeroed; bit-identical to the split
// version's two-term sum). Ft never touches global memory.
// 512 blocks = 2/CU all-resident (LDS 55.3 KB). XCD-chunked mapping.
__global__ __launch_bounds__(512) void rgf_interp_k(const float* __restrict__ Fu,
                                                    const float* __restrict__ ovf,
                                                    const float* __restrict__ img0,
                                                    const float* __restrict__ img2,
                                                    const float* __restrict__ filt0,
                                                    const float* __restrict__ filt1,
                                                    float* __restrict__ out) {
    __shared__ float acc[3][NROWS][WW];   // 55.3 KB
    int bid = blockIdx.x;                 // 512 blocks
    int slab = bid & 7;
    int side = slab >> 2;
    int b = slab & 3;
    int t0 = (bid >> 3) * BAND;
    int rbase = t0 - 2;                   // global row of acc row 0

    const float* Fx = Fu + side * 2 * NPIX + b * HWP;
    const float* Fyp = Fx + NPIX;

    float* A = &acc[0][0][0];
    for (int k = threadIdx.x; k < 3 * NROWS * WW; k += 512) A[k] = 0.0f;
    __syncthreads();

    // sources for target rows [t0-2, t0+BAND] with floor(fy) in [-M, M-1]:
    // s in [t0-2-(M-1), t0+BAND+M]  (56 rows interior)
    int sLo = max(t0 - 2 - (MBOUND - 1), 0);
    int sHi = min(t0 + BAND + MBOUND, HH - 1);
    int npairs = (sHi - sLo + 1) * 256;   // (row, col-pair) work items
    for (int k = threadIdx.x; k < npairs; k += 512) {
        int s = sLo + (k >> 8);
        int tx = k & 255;
        int rowoff = s * WW + 2 * tx;
        float2 fxv = *(const float2*)(Fx + rowoff);
        float2 fyv = *(const float2*)(Fyp + rowoff);
        float sf = (float)s;
        #pragma unroll
        for (int u = 0; u < 2; ++u) {
            int xx = 2 * tx + u;
            float fx = u ? fxv.y : fxv.x;
            float fy = u ? fyv.y : fyv.x;
            float x2 = __fadd_rn((float)xx, fx);
            float y2 = __fadd_rn(sf, fy);
            if (x2 >= 0.0f && x2 <= (float)(WW - 1) && y2 >= 0.0f && y2 <= (float)(HH - 1)
                && fy >= -(float)MBOUND && fy < (float)MBOUND) {
                int yf = (int)floorf(y2);
                int r = yf - rbase;
                if (r >= 0 && r < NROWS) {
                    int xf = (int)floorf(x2);
                    atomicAdd(&acc[0][r][xf], -fx);
                    atomicAdd(&acc[1][r][xf], -fy);
                    atomicAdd(&acc[2][r][xf], 1.0f);
                }
            }
        }
    }

    // replay exact overflow records landing in [max(rbase,0), min(t0+BAND,HH-1)]
    int n = ((const int*)ovf)[0];
    n = (n < 0) ? 0 : ((n > OV_CAP) ? OV_CAP : n);
    int lo = max(rbase, 0) * WW;
    int hi = (min(t0 + BAND, HH - 1) + 1) * WW;
    int keybase = side * NPIX + b * HWP;
    for (int i = threadIdx.x; i < n; i += 512) {
        int rel = ((const int*)ovf)[64 + i] - keybase;
        if (rel >= lo && rel < hi) {
            int r = rel / WW - rbase;
            int xf = rel % WW;
            atomicAdd(&acc[0][r][xf], ovf[64 + OV_CAP + i]);
            atomicAdd(&acc[1][r][xf], ovf[64 + 2 * OV_CAP + i]);
            atomicAdd(&acc[2][r][xf], 1.0f);
        }
    }
    __syncthreads();

    // (c) per-pixel fill + interp. Thread = column x, loop j over the 6 band
    // rows. acc is read-only from here (no further syncs needed).
    const float* img  = side ? img2  : img0;
    const float* filt = side ? filt1 : filt0;
    int x = threadIdx.x;                  // 0..511 == WW-1

    for (int j = 0; j < BAND; ++j) {
        int y = t0 + j;

        // --- in-LDS fill (bit-identical chain to fill2_k) ---
        float ax, ay, c;
        box_sum_lds(acc, rbase, y, x, ax, ay, c);
        float fx, fy;
        if (c > 0.0f) {
            fx = ax / c;
            fy = ay / c;
        } else {
            float nx = 0.0f, ny = 0.0f, den = 0.0f;
            float bx, by, bc;
            if (y > 0)      { box_sum_lds(acc, rbase, y - 1, x, bx, by, bc); if (bc > 0.0f) { nx += bx / bc; ny += by / bc; den += 1.0f; } }
            if (y < HH - 1) { box_sum_lds(acc, rbase, y + 1, x, bx, by, bc); if (bc > 0.0f) { nx += bx / bc; ny += by / bc; den += 1.0f; } }
            if (x > 0)      { box_sum_lds(acc, rbase, y, x - 1, bx, by, bc); if (bc > 0.0f) { nx += bx / bc; ny += by / bc; den += 1.0f; } }
            if (x < WW - 1) { box_sum_lds(acc, rbase, y, x + 1, bx, by, bc); if (bc > 0.0f) { nx += bx / bc; ny += by / bc; den += 1.0f; } }
            float inv = 1.0f / fmaxf(den, 1.0f);
            fx = nx * inv;
            fy = ny * inv;
        }

        // --- interp (identical body to the proven interp_k) ---
        float x2 = fminf(fmaxf((float)x + fx, 0.0f), (float)(WW - 1));
        float y2 = fminf(fmaxf((float)y + fy, 0.0f), (float)(HH - 1));
        float xff = floorf(x2), yff = floorf(y2);
        int xf = (int)xff, yf = (int)yff;
        float a  = x2 - xff;
        float bb = y2 - yff;
        float w00 = (1.0f - a) * (1.0f - bb);
        float w10 = a * (1.0f - bb);
        float w01 = (1.0f - a) * bb;
        float w11 = a * bb;

        float F[4][4];
        #pragma unroll
        for (int k = 0; k < 16; k++) {
            F[k >> 2][k & 3] = filt[((b * 16 + k) * HH + y) * WW + x];
        }
        float Cf[5][5];
        #pragma unroll
        for (int r = 0; r < 5; r++) {
            #pragma unroll
            for (int sc = 0; sc < 5; sc++) {
                float v = 0.0f;
                if (r < 4 && sc < 4)   v += w00 * F[r][sc];
                if (r < 4 && sc >= 1)  v += w10 * F[r][sc - 1];
                if (r >= 1 && sc < 4)  v += w01 * F[r - 1][sc];
                if (r >= 1 && sc >= 1) v += w11 * F[r - 1][sc - 1];
                Cf[r][sc] = v;
            }
        }
        int rows[5];
        #pragma unroll
        for (int r = 0; r < 5; r++) rows[r] = min(max(yf - 1 + r, 0), HH - 1);

        bool interior = (xf >= 1) && (xf <= WW - 4);
        if (interior) {
            int x0 = xf - 1;   // cols are x0..x0+4, all in-bounds
            #pragma unroll
            for (int ch = 0; ch < 3; ch++) {
                const float* ip = img + (b * 3 + ch) * HWP;
                float accv = 0.0f;
                #pragma unroll
                for (int r = 0; r < 5; r++) {
                    const float* rp = ip + rows[r] * WW + x0;
                    float wrow[5];
                    __builtin_memcpy(wrow, rp, 5 * sizeof(float));
                    #pragma unroll
                    for (int sc = 0; sc < 5; sc++) {
                        accv += Cf[r][sc] * wrow[sc];
                    }
                }
                unsafeAtomicAdd(&out[((b * 3 + ch) * HH + y) * WW + x], 0.5f * accv);
            }
        } else {
            int cols[5];
            #pragma unroll
            for (int sc = 0; sc < 5; sc++) cols[sc] = min(max(xf - 1 + sc, 0), WW - 1);
            #pragma unroll
            for (int ch = 0; ch < 3; ch++) {
                const float* ip = img + (b * 3 + ch) * HWP;
                float accv = 0.0f;
                #pragma unroll
                for (int r = 0; r < 5; r++) {
                    const float* rp = ip + rows[r] * WW;
                    #pragma unroll
                    for (int sc = 0; sc < 5; sc++) {
                        accv += Cf[r][sc] * rp[cols[sc]];
                    }
                }
                unsafeAtomicAdd(&out[((b * 3 + ch) * HH + y) * WW + x], 0.5f * accv);
            }
        }
    }
}

extern "C" void kernel_launch(void* const* d_in, const int* in_sizes, int n_in,
                              void* d_out, int out_size, void* d_ws, size_t ws_size,
                              hipStream_t stream) {
    const float* input0 = (const float*)d_in[0];
    const float* input2 = (const float*)d_in[1];
    const float* flow01 = (const float*)d_in[2];
    const float* flow10 = (const float*)d_in[3];
    const float* filt0  = (const float*)d_in[4];
    const float* filt1  = (const float*)d_in[5];
    float* out = (float*)d_out;

    float* ws = (float*)d_ws;
    float* Fu   = ws;                    // 4*NPIX floats: upsampled flow [side][comp][...]
    float* ovf  = ws + 4 * NPIX;         // 64 + 3*OV_CAP floats (1.57 MB) overflow list
                                         // total ws use ~14.2 MB (< previously-proven 25 MB)

    const int BS = 256;
    const int NBLK = (NPIX + BS - 1) / BS;

    // 4 stream ops total (was 5): memset out, memset ovf counter, upsample, fused
    hipMemsetAsync(out, 0, (size_t)3 * NPIX * sizeof(float), stream);
    hipMemsetAsync(ovf, 0, 256, stream);

    upsample_k<<<dim3(NBLK, 2), BS, 0, stream>>>(flow01, flow10, Fu, ovf);
    rgf_interp_k<<<dim3(2 * NB * NBANDS), 512, 0, stream>>>(
        Fu, ovf, input0, input2, filt0, filt1, out);
}